// Round 7
// baseline (243.347 us; speedup 1.0000x reference)
//
#include <hip/hip_runtime.h>

typedef unsigned short u16;
typedef unsigned int u32;
typedef __attribute__((ext_vector_type(4))) float f32x4;
typedef __attribute__((ext_vector_type(8))) short s16x8;
typedef __attribute__((ext_vector_type(4))) u16 u16x4;
typedef __attribute__((ext_vector_type(2))) u32 u32x2;

#define L2E 1.4426950408889634f
#define QSCALE 0.18033688011112042f /* (1/8) * log2(e) */

__device__ __forceinline__ u16 f2bf(float f) {  // RNE
    union { float f; u32 i; } v; v.f = f;
    return (u16)((v.i + 0x7fffu + ((v.i >> 16) & 1u)) >> 16);
}
// pack hi16(a) | hi16(b)<<16 — single v_perm_b32
__device__ __forceinline__ u32 pack_hi(float a, float b) {
    union { float f; u32 i; } x, y; x.f = a; y.f = b;
    return __builtin_amdgcn_perm(y.i, x.i, 0x07060302u);
}
// bf16 stored in lo/hi half of a u32 -> f32 (1 VALU op each)
__device__ __forceinline__ float bflo(u32 w) {
    union { u32 i; float f; } v; v.i = w << 16; return v.f;
}
__device__ __forceinline__ float bfhi(u32 w) {
    union { u32 i; float f; } v; v.i = w & 0xFFFF0000u; return v.f;
}

// async global->LDS, 16B per lane; LDS dest = wave-uniform base + lane*16
__device__ __forceinline__ void gl2lds16(const u16* g, u16* l) {
    __builtin_amdgcn_global_load_lds(
        (const __attribute__((address_space(1))) void*)g,
        (__attribute__((address_space(3))) void*)l, 16, 0, 0);
}

// ---------------------------------------------------------------------------
// prep_kernel = conv (blocks 0..9215) + lg (blocks 9216..13311).
// ---------------------------------------------------------------------------
__global__ __launch_bounds__(256) void prep_kernel(
    const float* __restrict__ s0, const float* __restrict__ s1,
    const float* __restrict__ s2, const float* __restrict__ s3,
    const float* __restrict__ s4, const float* __restrict__ s5,
    u16* __restrict__ dst,
    const float* __restrict__ SC, const float* __restrict__ gwp,
    const float* __restrict__ gbp, u16* __restrict__ LGx)
{
    if (blockIdx.x < 9216) {
        int e = (blockIdx.x * 256 + threadIdx.x) * 4;
        const float* src; int off;
        if      (e < 4194304) { src = s0; off = e; }
        else if (e < 8388608) { src = s1; off = e - 4194304; }
        else if (e < 8650752) { src = s2; off = e - 8388608; }
        else if (e < 8912896) { src = s3; off = e - 8650752; }
        else if (e < 9175040) { src = s4; off = e - 8912896; }
        else                  { src = s5; off = e - 9175040; }
        f32x4 f = *(const f32x4*)(src + off);
        u16x4 o;
#pragma unroll
        for (int j = 0; j < 4; ++j) o[j] = f2bf(f[j]);
        *(u16x4*)(dst + e) = o;
    } else {
        const int flat = (blockIdx.x - 9216) * 256 + threadIdx.x;
        const int lane = flat & 63;
        const int kt   = (flat >> 6) & 31;
        const int t16  = (flat >> 11) & 127;
        const int b    = flat >> 18;
        const int l16 = lane & 15, quad = lane >> 4;
        const float tA = -gwp[0] * L2E, tB = -gbp[0] * L2E;
        const float* row = SC + ((size_t)b * 2048 + t16 * 16 + l16) * 2048
                              + kt * 64 + quad * 4;
        __align__(16) u16 tmp[16];
#pragma unroll
        for (int kk = 0; kk < 4; ++kk) {
            f32x4 x = *(const f32x4*)(row + kk * 16);
#pragma unroll
            for (int reg = 0; reg < 4; ++reg) {
                float g = __builtin_amdgcn_rcpf(
                    1.0f + __builtin_amdgcn_exp2f(tA * x[reg] + tB)) + 1e-8f;
                tmp[kk * 4 + reg] = f2bf(__builtin_amdgcn_logf(g));  // log2
            }
        }
        u16* d = LGx + (size_t)flat * 16;
        *(uint4*)d       = *(uint4*)tmp;
        *(uint4*)(d + 8) = *(uint4*)(tmp + 8);
    }
}

// ---------------------------------------------------------------------------
// GEMM core, double-buffered: C[128x128] = A[128x512]*B^T, bf16.
// ---------------------------------------------------------------------------
__device__ __forceinline__ void gemm_core(
    const u16* __restrict__ A, const u16* __restrict__ Bw,
    int m0, int n0, u16* As, u16* Bs, f32x4 acc[4][4])
{
    const int tid = threadIdx.x;
    const int lane = tid & 63, w = tid >> 6;
    const int wm = w >> 1, wn = w & 1;
    const int l16 = lane & 15, quad = lane >> 4;
    const int srow = (lane >> 2), sch = (lane & 3) * 8;
    const f32x4 vzero = {0.f, 0.f, 0.f, 0.f};
#pragma unroll
    for (int i = 0; i < 4; ++i)
#pragma unroll
        for (int j = 0; j < 4; ++j) acc[i][j] = vzero;

#pragma unroll
    for (int j = 0; j < 2; ++j) {
        int row = w * 32 + j * 16 + srow;
        gl2lds16(&A[(size_t)(m0 + row) * 512 + sch], &As[w * 1024 + j * 512]);
        gl2lds16(&Bw[(size_t)(n0 + row) * 512 + sch], &Bs[w * 1024 + j * 512]);
    }
    for (int kt = 0; kt < 16; ++kt) {
        __syncthreads();
        const int cur = (kt & 1) * 4096;
        if (kt < 15) {
            const int nxt = ((kt + 1) & 1) * 4096;
#pragma unroll
            for (int j = 0; j < 2; ++j) {
                int row = w * 32 + j * 16 + srow;
                gl2lds16(&A[(size_t)(m0 + row) * 512 + (kt + 1) * 32 + sch],
                         &As[nxt + w * 1024 + j * 512]);
                gl2lds16(&Bw[(size_t)(n0 + row) * 512 + (kt + 1) * 32 + sch],
                         &Bs[nxt + w * 1024 + j * 512]);
            }
        }
        s16x8 af[4], bfr[4];
#pragma unroll
        for (int mt = 0; mt < 4; ++mt)
            af[mt] = *(const s16x8*)&As[cur + (wm * 64 + mt * 16 + l16) * 32 + quad * 8];
#pragma unroll
        for (int nt = 0; nt < 4; ++nt)
            bfr[nt] = *(const s16x8*)&Bs[cur + (wn * 64 + nt * 16 + l16) * 32 + quad * 8];
#pragma unroll
        for (int mt = 0; mt < 4; ++mt)
#pragma unroll
            for (int nt = 0; nt < 4; ++nt)
                acc[mt][nt] = __builtin_amdgcn_mfma_f32_16x16x32_bf16(
                    af[mt], bfr[nt], acc[mt][nt], 0, 0, 0);
    }
}

// ---------------------------------------------------------------------------
// GEMM core, M=64 tiles: C[64x128] = A[64x512]*B^T. 2 blocks/CU for out_kernel
// (the 128x128 version at grid=256 left 1 block/CU -> naked latency stalls).
// ---------------------------------------------------------------------------
__device__ __forceinline__ void gemm_core_m64(
    const u16* __restrict__ A, const u16* __restrict__ Bw,
    int m0, int n0, u16* As, u16* Bs, f32x4 acc[2][4])
{
    const int tid = threadIdx.x;
    const int lane = tid & 63, w = tid >> 6;
    const int wm = w & 1, wn = w >> 1;
    const int l16 = lane & 15, quad = lane >> 4;
    const int srow = (lane >> 2), sch = (lane & 3) * 8;
    const f32x4 vzero = {0.f, 0.f, 0.f, 0.f};
#pragma unroll
    for (int i = 0; i < 2; ++i)
#pragma unroll
        for (int j = 0; j < 4; ++j) acc[i][j] = vzero;

    gl2lds16(&A[(size_t)(m0 + w * 16 + srow) * 512 + sch], &As[w * 512]);
#pragma unroll
    for (int j = 0; j < 2; ++j) {
        int row = w * 32 + j * 16 + srow;
        gl2lds16(&Bw[(size_t)(n0 + row) * 512 + sch], &Bs[w * 1024 + j * 512]);
    }
    for (int kt = 0; kt < 16; ++kt) {
        __syncthreads();
        const int curA = (kt & 1) * 2048, curB = (kt & 1) * 4096;
        if (kt < 15) {
            const int nxtA = ((kt + 1) & 1) * 2048, nxtB = ((kt + 1) & 1) * 4096;
            gl2lds16(&A[(size_t)(m0 + w * 16 + srow) * 512 + (kt + 1) * 32 + sch],
                     &As[nxtA + w * 512]);
#pragma unroll
            for (int j = 0; j < 2; ++j) {
                int row = w * 32 + j * 16 + srow;
                gl2lds16(&Bw[(size_t)(n0 + row) * 512 + (kt + 1) * 32 + sch],
                         &Bs[nxtB + w * 1024 + j * 512]);
            }
        }
        s16x8 af[2], bfr[4];
#pragma unroll
        for (int mt = 0; mt < 2; ++mt)
            af[mt] = *(const s16x8*)&As[curA + (wm * 32 + mt * 16 + l16) * 32 + quad * 8];
#pragma unroll
        for (int nt = 0; nt < 4; ++nt)
            bfr[nt] = *(const s16x8*)&Bs[curB + (wn * 64 + nt * 16 + l16) * 32 + quad * 8];
#pragma unroll
        for (int mt = 0; mt < 2; ++mt)
#pragma unroll
            for (int nt = 0; nt < 4; ++nt)
                acc[mt][nt] = __builtin_amdgcn_mfma_f32_16x16x32_bf16(
                    af[mt], bfr[nt], acc[mt][nt], 0, 0, 0);
    }
}

// ---------------------------------------------------------------------------
// QKV projection. job 0=Q (scaled, ->[B,H,N,64]), 1=K, 2=V (-> [B,H,64,N]).
// ---------------------------------------------------------------------------
__global__ __launch_bounds__(256) void proj_kernel(
    const u16* __restrict__ cQin, const u16* __restrict__ cKV,
    const u16* __restrict__ cW,
    const float* __restrict__ bq, const float* __restrict__ bk,
    const float* __restrict__ bv,
    u16* __restrict__ Qh, u16* __restrict__ Kh, u16* __restrict__ Vt)
{
    __shared__ __align__(16) u16 As[2 * 4096];
    __shared__ __align__(16) u16 Bs[2 * 4096];
    const int job = blockIdx.z;
    const u16* A = (job == 0) ? cQin : cKV;
    const u16* W = cW + (size_t)job * 262144;
    const float* bias = (job == 0) ? bq : (job == 1 ? bk : bv);
    const int m0 = blockIdx.y * 128, n0 = blockIdx.x * 128;
    f32x4 acc[4][4];
    gemm_core(A, W, m0, n0, As, Bs, acc);

    const int tid = threadIdx.x, lane = tid & 63, w = tid >> 6;
    const int wm = w >> 1, wn = w & 1, l16 = lane & 15, quad = lane >> 4;
#pragma unroll
    for (int nt = 0; nt < 4; ++nt) {
        int j = n0 + wn * 64 + nt * 16 + l16;
        float bj = bias[j];
        int h = j >> 6, d = j & 63;
#pragma unroll
        for (int mt = 0; mt < 4; ++mt) {
            int trow = m0 + wm * 64 + mt * 16 + quad * 4;
            int bb = trow >> 11, nn = trow & 2047;
            int bh = bb * 8 + h;
            if (job == 2) {
                u16x4 pv;
#pragma unroll
                for (int reg = 0; reg < 4; ++reg) pv[reg] = f2bf(acc[mt][nt][reg] + bj);
                *(u16x4*)&Vt[(size_t)(bh * 64 + d) * 2048 + nn] = pv;
            } else if (job == 0) {
#pragma unroll
                for (int reg = 0; reg < 4; ++reg)
                    Qh[(size_t)(bh * 2048 + nn + reg) * 64 + d] =
                        f2bf((acc[mt][nt][reg] + bj) * QSCALE);
            } else {
#pragma unroll
                for (int reg = 0; reg < 4; ++reg)
                    Kh[(size_t)(bh * 2048 + nn + reg) * 64 + d] =
                        f2bf(acc[mt][nt][reg] + bj);
            }
        }
    }
}

// ---------------------------------------------------------------------------
// Attention, software-pipelined one tile deep (T15-style).
// Block = 256 thr = 4 fat waves (32 q each, 2 groups); grid (16,8,4) = 2/CU.
// KVBLK=128, 16 tiles. Iter kt: stage K(kt+1)&V(kt); QK(kt)+exp2+pack->Pw(kt);
// PV(kt-1) from Pw(kt-1)  [independent of QK(kt) -> MFMA/VALU co-schedule,
// breaking the phase-lock that kept all prior versions at VALU-cyc+MFMA-cyc
// serialized ~52us]. V staged one iter later than K so K[2]+V[2] suffice;
// slot offsets all compile-time via manual unroll-by-2 (named Pw sets).
// All layouts/swizzles/arithmetic identical to the verified R5 kernel;
// tile accumulation order unchanged => bit-identical results.
// ---------------------------------------------------------------------------
__global__ __launch_bounds__(256, 2) void attn_kernel(
    const u16* __restrict__ Qh, const u16* __restrict__ Kh,
    const u16* __restrict__ Vt, const u16* __restrict__ LGx,
    u16* __restrict__ Ob)
{
    __shared__ __align__(16) u16 Ks[2 * 8192];  // [slot][key(128)][d(64)] swz
    __shared__ __align__(16) u16 Vs[2 * 8192];  // [slot][half][d(64)][key(64)] swz
    const int tid = threadIdx.x;
    const int w = tid >> 6, lane = tid & 63;
    const int l16 = lane & 15, quad = lane >> 4;
    const int b = blockIdx.z, head = blockIdx.y, qg = blockIdx.x;
    const int bh = b * 8 + head;
    const int q0a = qg * 128 + w * 32, q0b = q0a + 16;
    const int t16a = qg * 8 + w * 2;
    const u16* Qp = Qh + (size_t)bh * 131072;
    const u16* Kp = Kh + (size_t)bh * 131072;
    const u16* Vp = Vt + (size_t)bh * 131072;
    const u16* lgPa = LGx + ((size_t)((b * 128 + t16a) * 32) * 64 + lane) * 16;
    const u16* lgPb = LGx + ((size_t)((b * 128 + t16a + 1) * 32) * 64 + lane) * 16;
    const f32x4 vzero = {0.f, 0.f, 0.f, 0.f};
    const s16x8 ones = {0x3F80, 0x3F80, 0x3F80, 0x3F80,
                        0x3F80, 0x3F80, 0x3F80, 0x3F80};  // bf16 1.0 x8

    // precomputed LDS read bases (u16 units); V formulas == K's
    const int s3 = l16 & 7, s2x = s3 & 3, s4x = s3 & 4;
    const int qsw = (quad ^ s2x) * 8;
    const int rb0 = l16 * 64 + qsw + s4x * 8;          // kc even
    const int rb1 = l16 * 64 + qsw + (4 ^ s4x) * 8;    // kc odd
    u16* KsF = &Ks[0];
    u16* VsF = &Vs[0];

    // staging: waves 0-1 K halves, waves 2-3 V halves; 8 slabs each
    const int sr = lane >> 3, c8 = lane & 7;           // 8 rows x 8 chunks
    const bool isK = (w < 2);
    const int hv = w & 1;
    const u16* sgq = isK
        ? (Kp + (size_t)(hv * 64 + sr) * 64 + (c8 ^ sr) * 8)
        : (Vp + (size_t)sr * 2048 + hv * 64 + (c8 ^ sr) * 8);
    const size_t slabAdv = isK ? 512 : 16384;  // +8 rows (u16)
    const size_t tileAdv = isK ? 8192 : 128;   // next 128-key tile (u16)

    s16x8 qfa0 = *(const s16x8*)&Qp[(size_t)(q0a + l16) * 64 + quad * 8];
    s16x8 qfa1 = *(const s16x8*)&Qp[(size_t)(q0a + l16) * 64 + 32 + quad * 8];
    s16x8 qfb0 = *(const s16x8*)&Qp[(size_t)(q0b + l16) * 64 + quad * 8];
    s16x8 qfb1 = *(const s16x8*)&Qp[(size_t)(q0b + l16) * 64 + 32 + quad * 8];
    f32x4 oA[4], oB[4], laccA = vzero, laccB = vzero;
#pragma unroll
    for (int dn = 0; dn < 4; ++dn) { oA[dn] = vzero; oB[dn] = vzero; }

    // prologue: K-waves stage K(0) -> slot0; V-waves idle; lg(0) regs
    if (isK) {
        u16* db = KsF + hv * 4096;
#pragma unroll
        for (int j = 0; j < 8; ++j)
            gl2lds16(sgq + (size_t)j * slabAdv, db + j * 512);
        sgq += tileAdv;
    }
    uint4 lga0 = *(const uint4*)lgPa;
    uint4 lga1 = *(const uint4*)(lgPa + 8);
    uint4 lga2 = *(const uint4*)(lgPa + 1024);
    uint4 lga3 = *(const uint4*)(lgPa + 1032);
    uint4 lgb0 = *(const uint4*)lgPb;
    uint4 lgb1 = *(const uint4*)(lgPb + 8);
    uint4 lgb2 = *(const uint4*)(lgPb + 1024);
    uint4 lgb3 = *(const uint4*)(lgPb + 1032);
    lgPa += 2048; lgPb += 2048;
    u32 PA0[8][2], PB0[8][2], PA1[8][2], PB1[8][2];

// QK quarter for both q-groups: raw S^T with LG C-init, exp2, pack -> PAp/PBp
#define QKPART(BO, PAp, PBp, LA, LB, MA, MB, KOFF)                             \
    {                                                                          \
        const u32 wda[8] = {LA.x, LA.y, LA.z, LA.w, LB.x, LB.y, LB.z, LB.w};   \
        const u32 wdb[8] = {MA.x, MA.y, MA.z, MA.w, MB.x, MB.y, MB.z, MB.w};   \
        _Pragma("unroll")                                                      \
        for (int kk = 0; kk < 4; ++kk) {                                       \
            s16x8 ka = *(const s16x8*)(KsF + (BO) + rb0 + (KOFF + kk) * 1024); \
            s16x8 kb = *(const s16x8*)(KsF + (BO) + rb1 + (KOFF + kk) * 1024); \
            f32x4 ci;                                                          \
            ci[0] = bflo(wda[kk * 2]);     ci[1] = bfhi(wda[kk * 2]);          \
            ci[2] = bflo(wda[kk * 2 + 1]); ci[3] = bfhi(wda[kk * 2 + 1]);      \
            f32x4 s = __builtin_amdgcn_mfma_f32_16x16x32_bf16(ka, qfa0, ci, 0, 0, 0); \
            s = __builtin_amdgcn_mfma_f32_16x16x32_bf16(kb, qfa1, s, 0, 0, 0); \
            f32x4 cj;                                                          \
            cj[0] = bflo(wdb[kk * 2]);     cj[1] = bfhi(wdb[kk * 2]);          \
            cj[2] = bflo(wdb[kk * 2 + 1]); cj[3] = bfhi(wdb[kk * 2 + 1]);      \
            f32x4 t = __builtin_amdgcn_mfma_f32_16x16x32_bf16(ka, qfb0, cj, 0, 0, 0); \
            t = __builtin_amdgcn_mfma_f32_16x16x32_bf16(kb, qfb1, t, 0, 0, 0); \
            PAp[KOFF + kk][0] = pack_hi(__builtin_amdgcn_exp2f(s[0]),          \
                                        __builtin_amdgcn_exp2f(s[1]));         \
            PAp[KOFF + kk][1] = pack_hi(__builtin_amdgcn_exp2f(s[2]),          \
                                        __builtin_amdgcn_exp2f(s[3]));         \
            PBp[KOFF + kk][0] = pack_hi(__builtin_amdgcn_exp2f(t[0]),          \
                                        __builtin_amdgcn_exp2f(t[1]));         \
            PBp[KOFF + kk][1] = pack_hi(__builtin_amdgcn_exp2f(t[2]),          \
                                        __builtin_amdgcn_exp2f(t[3]));         \
        }                                                                      \
    }

// PV of the PREVIOUS tile from consumed Pw set; V slot offset VRO
#define PVPART(VRO, PAc, PBc)                                                  \
    {                                                                          \
        _Pragma("unroll")                                                      \
        for (int kc = 0; kc < 4; ++kc) {                                       \
            union { u32 wrd[4]; s16x8 v; } pa, pb;                             \
            _Pragma("unroll")                                                  \
            for (int i = 0; i < 2; ++i) {                                      \
                u32x2 r1 = __builtin_amdgcn_permlane32_swap(                   \
                    PAc[2 * kc][i], PAc[2 * kc + 1][i], false, false);         \
                u32x2 r2 = __builtin_amdgcn_permlane16_swap(r1[0], r1[1], false, false); \
                pa.wrd[i] = r2[0]; pa.wrd[2 + i] = r2[1];                      \
                u32x2 r3 = __builtin_amdgcn_permlane32_swap(                   \
                    PBc[2 * kc][i], PBc[2 * kc + 1][i], false, false);         \
                u32x2 r4 = __builtin_amdgcn_permlane16_swap(r3[0], r3[1], false, false); \
                pb.wrd[i] = r4[0]; pb.wrd[2 + i] = r4[1];                      \
            }                                                                  \
            s16x8 pfa = pa.v, pfb = pb.v;                                      \
            laccA = __builtin_amdgcn_mfma_f32_16x16x32_bf16(pfa, ones, laccA, 0, 0, 0); \
            laccB = __builtin_amdgcn_mfma_f32_16x16x32_bf16(pfb, ones, laccB, 0, 0, 0); \
            const int vbb = ((kc & 1) ? rb1 : rb0) + (kc >> 1) * 4096 + (VRO); \
            _Pragma("unroll")                                                  \
            for (int dn = 0; dn < 4; ++dn) {                                   \
                s16x8 vf = *(const s16x8*)(VsF + vbb + dn * 1024);             \
                oA[dn] = __builtin_amdgcn_mfma_f32_16x16x32_bf16(pfa, vf, oA[dn], 0, 0, 0); \
                oB[dn] = __builtin_amdgcn_mfma_f32_16x16x32_bf16(pfb, vf, oB[dn], 0, 0, 0); \
            }                                                                  \
        }                                                                      \
    }

// Body for tile KT: BO = (KT&1)*8192. Stages K(KT+1)->slot(8192-BO) [guard
// DOKST], V(KT)->slot BO [always]. QK(KT)->PwP. PV(KT-1) from PwC [DOPV],
// reading V slot (8192-BO). All slot pairs disjoint within the barrier window.
#define AB(BO, PAp, PBp, PAc, PBc, DOPV, DOKST, DOLG)                          \
    {                                                                          \
        if (isK) {                                                             \
            if (DOKST) {                                                       \
                u16* db = KsF + (8192 - (BO)) + hv * 4096;                     \
                _Pragma("unroll")                                              \
                for (int j = 0; j < 8; ++j)                                    \
                    gl2lds16(sgq + (size_t)j * 512, db + j * 512);             \
                sgq += 8192;                                                   \
            }                                                                  \
        } else {                                                               \
            u16* db = VsF + (BO) + hv * 4096;                                  \
            _Pragma("unroll")                                                  \
            for (int j = 0; j < 8; ++j)                                        \
                gl2lds16(sgq + (size_t)j * 16384, db + j * 512);               \
            sgq += 128;                                                        \
        }                                                                      \
        __builtin_amdgcn_s_setprio(1);                                         \
        QKPART(BO, PAp, PBp, lga0, lga1, lgb0, lgb1, 0);                       \
        QKPART(BO, PAp, PBp, lga2, lga3, lgb2, lgb3, 4);                       \
        if (DOLG) {                                                            \
            lga0 = *(const uint4*)lgPa; lga1 = *(const uint4*)(lgPa + 8);      \
            lga2 = *(const uint4*)(lgPa + 1024); lga3 = *(const uint4*)(lgPa + 1032); \
            lgb0 = *(const uint4*)lgPb; lgb1 = *(const uint4*)(lgPb + 8);      \
            lgb2 = *(const uint4*)(lgPb + 1024); lgb3 = *(const uint4*)(lgPb + 1032); \
            lgPa += 2048; lgPb += 2048;                                        \
        }                                                                      \
        if (DOPV) { PVPART((8192 - (BO)), PAc, PBc); }                         \
        __builtin_amdgcn_s_setprio(0);                                         \
        __syncthreads();                                                       \
    }

    __syncthreads();                               // K(0) staged
    AB(0,    PA0, PB0, PA1, PB1, false, true, true)            // kt = 0
    AB(8192, PA1, PB1, PA0, PB0, true,  true, true)            // kt = 1
    for (int kt2 = 2; kt2 < 16; kt2 += 2) {
        AB(0,    PA0, PB0, PA1, PB1, true, true, true)         // kt2 (even)
        AB(8192, PA1, PB1, PA0, PB0, true, (kt2 < 14), (kt2 < 14))  // kt2+1
    }
    PVPART(8192, PA1, PB1)                          // tile 15, V slot 1
#undef AB
#undef QKPART
#undef PVPART

    // lacc[reg] = sum_k P[q=quad*4+reg][k] — exactly the row this lane stores
#pragma unroll
    for (int reg = 0; reg < 4; ++reg) {
        float invA = __builtin_amdgcn_rcpf(laccA[reg]);
        float invB = __builtin_amdgcn_rcpf(laccB[reg]);
        int trowA = b * 2048 + q0a + quad * 4 + reg;
        int trowB = b * 2048 + q0b + quad * 4 + reg;
#pragma unroll
        for (int dn = 0; dn < 4; ++dn) {
            Ob[(size_t)trowA * 512 + head * 64 + dn * 16 + l16] =
                f2bf(oA[dn][reg] * invA);
            Ob[(size_t)trowB * 512 + head * 64 + dn * 16 + l16] =
                f2bf(oB[dn][reg] * invB);
        }
    }
}

// ---------------------------------------------------------------------------
// Output projection: out = Ob @ Wo^T + bo, fp32 out. 64x128 tiles, 2 blocks/CU.
// ---------------------------------------------------------------------------
__global__ __launch_bounds__(256) void out_kernel(
    const u16* __restrict__ Ob, const u16* __restrict__ cWo,
    const float* __restrict__ bo, float* __restrict__ out)
{
    __shared__ __align__(16) u16 As[2 * 2048];
    __shared__ __align__(16) u16 Bs[2 * 4096];
    const int m0 = blockIdx.y * 64, n0 = blockIdx.x * 128;
    f32x4 acc[2][4];
    gemm_core_m64(Ob, cWo, m0, n0, As, Bs, acc);
    const int tid = threadIdx.x, lane = tid & 63, w = tid >> 6;
    const int wm = w & 1, wn = w >> 1, l16 = lane & 15, quad = lane >> 4;
#pragma unroll
    for (int nt = 0; nt < 4; ++nt) {
        int j = n0 + wn * 64 + nt * 16 + l16;
        float bj = bo[j];
#pragma unroll
        for (int mt = 0; mt < 2; ++mt) {
            int t = m0 + wm * 32 + mt * 16 + quad * 4;
#pragma unroll
            for (int reg = 0; reg < 4; ++reg)
                out[(size_t)(t + reg) * 512 + j] = acc[mt][nt][reg] + bj;
        }
    }
}

extern "C" void kernel_launch(void* const* d_in, const int* in_sizes, int n_in,
                              void* d_out, int out_size, void* d_ws, size_t ws_size,
                              hipStream_t stream)
{
    const float* Qin  = (const float*)d_in[0];
    const float* KVin = (const float*)d_in[1];
    const float* SC   = (const float*)d_in[2];
    const float* Wq   = (const float*)d_in[3];
    const float* bq   = (const float*)d_in[4];
    const float* Wk   = (const float*)d_in[5];
    const float* bk   = (const float*)d_in[6];
    const float* Wv   = (const float*)d_in[7];
    const float* bv   = (const float*)d_in[8];
    const float* gw   = (const float*)d_in[9];
    const float* gb   = (const float*)d_in[10];
    const float* Wo   = (const float*)d_in[11];
    const float* bo   = (const float*)d_in[12];
    float* out = (float*)d_out;

    // ws layout (u16 units): conv 9.4M | Qh/Kh/Vt/Ob 4.2M each | LGx 16.8M
    u16* conv = (u16*)d_ws;
    u16* cQin = conv;
    u16* cKV  = conv + 4194304;
    u16* cW   = conv + 8388608;        // Wq,Wk,Wv,Wo each 262,144
    u16* Qh   = conv + 9437184;
    u16* Kh   = Qh + 4194304;
    u16* Vt   = Kh + 4194304;
    u16* Ob   = Vt + 4194304;
    u16* LGx  = Ob + 4194304;          // 16,777,216 u16 = 32 MiB

    hipLaunchKernelGGL(prep_kernel, dim3(13312), dim3(256), 0, stream,
                       Qin, KVin, Wq, Wk, Wv, Wo, conv, SC, gw, gb, LGx);
    hipLaunchKernelGGL(proj_kernel, dim3(4, 64, 3), dim3(256), 0, stream,
                       cQin, cKV, cW, bq, bk, bv, Qh, Kh, Vt);
    hipLaunchKernelGGL(attn_kernel, dim3(16, 8, 4), dim3(256), 0, stream,
                       Qh, Kh, Vt, LGx, Ob);
    hipLaunchKernelGGL(out_kernel, dim3(4, 128), dim3(256), 0, stream,
                       Ob, cW + 786432, bo, out);
}

// Round 8
// 235.867 us; speedup vs baseline: 1.0317x; 1.0317x over previous
//
#include <hip/hip_runtime.h>

typedef unsigned short u16;
typedef unsigned int u32;
typedef __attribute__((ext_vector_type(4))) float f32x4;
typedef __attribute__((ext_vector_type(8))) short s16x8;
typedef __attribute__((ext_vector_type(4))) u16 u16x4;
typedef __attribute__((ext_vector_type(2))) u32 u32x2;

#define L2E 1.4426950408889634f
#define QSCALE 0.18033688011112042f /* (1/8) * log2(e) */

__device__ __forceinline__ u16 f2bf(float f) {  // RNE
    union { float f; u32 i; } v; v.f = f;
    return (u16)((v.i + 0x7fffu + ((v.i >> 16) & 1u)) >> 16);
}
// pack hi16(a) | hi16(b)<<16 — single v_perm_b32
__device__ __forceinline__ u32 pack_hi(float a, float b) {
    union { float f; u32 i; } x, y; x.f = a; y.f = b;
    return __builtin_amdgcn_perm(y.i, x.i, 0x07060302u);
}
// bf16 stored in lo/hi half of a u32 -> f32 (1 VALU op each)
__device__ __forceinline__ float bflo(u32 w) {
    union { u32 i; float f; } v; v.i = w << 16; return v.f;
}
__device__ __forceinline__ float bfhi(u32 w) {
    union { u32 i; float f; } v; v.i = w & 0xFFFF0000u; return v.f;
}

// async global->LDS, 16B per lane; LDS dest = wave-uniform base + lane*16
__device__ __forceinline__ void gl2lds16(const u16* g, u16* l) {
    __builtin_amdgcn_global_load_lds(
        (const __attribute__((address_space(1))) void*)g,
        (__attribute__((address_space(3))) void*)l, 16, 0, 0);
}

// ---------------------------------------------------------------------------
// conv_kernel: 6 fp32 tensors (Qin,KVin,Wq,Wk,Wv,Wo) -> bf16 flat region.
// (The gate/log LGx work moved into projlg_kernel to overlap with the GEMM.)
// ---------------------------------------------------------------------------
__global__ __launch_bounds__(256) void conv_kernel(
    const float* __restrict__ s0, const float* __restrict__ s1,
    const float* __restrict__ s2, const float* __restrict__ s3,
    const float* __restrict__ s4, const float* __restrict__ s5,
    u16* __restrict__ dst)
{
    int e = (blockIdx.x * 256 + threadIdx.x) * 4;
    const float* src; int off;
    if      (e < 4194304) { src = s0; off = e; }
    else if (e < 8388608) { src = s1; off = e - 4194304; }
    else if (e < 8650752) { src = s2; off = e - 8388608; }
    else if (e < 8912896) { src = s3; off = e - 8650752; }
    else if (e < 9175040) { src = s4; off = e - 8912896; }
    else                  { src = s5; off = e - 9175040; }
    f32x4 f = *(const f32x4*)(src + off);
    u16x4 o;
#pragma unroll
    for (int j = 0; j < 4; ++j) o[j] = f2bf(f[j]);
    *(u16x4*)(dst + e) = o;
}

// ---------------------------------------------------------------------------
// GEMM core, double-buffered: C[128x128] = A[128x512]*B^T, bf16.
// ---------------------------------------------------------------------------
__device__ __forceinline__ void gemm_core(
    const u16* __restrict__ A, const u16* __restrict__ Bw,
    int m0, int n0, u16* As, u16* Bs, f32x4 acc[4][4])
{
    const int tid = threadIdx.x;
    const int lane = tid & 63, w = tid >> 6;
    const int wm = w >> 1, wn = w & 1;
    const int l16 = lane & 15, quad = lane >> 4;
    const int srow = (lane >> 2), sch = (lane & 3) * 8;
    const f32x4 vzero = {0.f, 0.f, 0.f, 0.f};
#pragma unroll
    for (int i = 0; i < 4; ++i)
#pragma unroll
        for (int j = 0; j < 4; ++j) acc[i][j] = vzero;

#pragma unroll
    for (int j = 0; j < 2; ++j) {
        int row = w * 32 + j * 16 + srow;
        gl2lds16(&A[(size_t)(m0 + row) * 512 + sch], &As[w * 1024 + j * 512]);
        gl2lds16(&Bw[(size_t)(n0 + row) * 512 + sch], &Bs[w * 1024 + j * 512]);
    }
    for (int kt = 0; kt < 16; ++kt) {
        __syncthreads();
        const int cur = (kt & 1) * 4096;
        if (kt < 15) {
            const int nxt = ((kt + 1) & 1) * 4096;
#pragma unroll
            for (int j = 0; j < 2; ++j) {
                int row = w * 32 + j * 16 + srow;
                gl2lds16(&A[(size_t)(m0 + row) * 512 + (kt + 1) * 32 + sch],
                         &As[nxt + w * 1024 + j * 512]);
                gl2lds16(&Bw[(size_t)(n0 + row) * 512 + (kt + 1) * 32 + sch],
                         &Bs[nxt + w * 1024 + j * 512]);
            }
        }
        s16x8 af[4], bfr[4];
#pragma unroll
        for (int mt = 0; mt < 4; ++mt)
            af[mt] = *(const s16x8*)&As[cur + (wm * 64 + mt * 16 + l16) * 32 + quad * 8];
#pragma unroll
        for (int nt = 0; nt < 4; ++nt)
            bfr[nt] = *(const s16x8*)&Bs[cur + (wn * 64 + nt * 16 + l16) * 32 + quad * 8];
#pragma unroll
        for (int mt = 0; mt < 4; ++mt)
#pragma unroll
            for (int nt = 0; nt < 4; ++nt)
                acc[mt][nt] = __builtin_amdgcn_mfma_f32_16x16x32_bf16(
                    af[mt], bfr[nt], acc[mt][nt], 0, 0, 0);
    }
}

// ---------------------------------------------------------------------------
// GEMM core, M=64 tiles: C[64x128] = A[64x512]*B^T. 2 blocks/CU for out_kernel.
// ---------------------------------------------------------------------------
__device__ __forceinline__ void gemm_core_m64(
    const u16* __restrict__ A, const u16* __restrict__ Bw,
    int m0, int n0, u16* As, u16* Bs, f32x4 acc[2][4])
{
    const int tid = threadIdx.x;
    const int lane = tid & 63, w = tid >> 6;
    const int wm = w & 1, wn = w >> 1;
    const int l16 = lane & 15, quad = lane >> 4;
    const int srow = (lane >> 2), sch = (lane & 3) * 8;
    const f32x4 vzero = {0.f, 0.f, 0.f, 0.f};
#pragma unroll
    for (int i = 0; i < 2; ++i)
#pragma unroll
        for (int j = 0; j < 4; ++j) acc[i][j] = vzero;

    gl2lds16(&A[(size_t)(m0 + w * 16 + srow) * 512 + sch], &As[w * 512]);
#pragma unroll
    for (int j = 0; j < 2; ++j) {
        int row = w * 32 + j * 16 + srow;
        gl2lds16(&Bw[(size_t)(n0 + row) * 512 + sch], &Bs[w * 1024 + j * 512]);
    }
    for (int kt = 0; kt < 16; ++kt) {
        __syncthreads();
        const int curA = (kt & 1) * 2048, curB = (kt & 1) * 4096;
        if (kt < 15) {
            const int nxtA = ((kt + 1) & 1) * 2048, nxtB = ((kt + 1) & 1) * 4096;
            gl2lds16(&A[(size_t)(m0 + w * 16 + srow) * 512 + (kt + 1) * 32 + sch],
                     &As[nxtA + w * 512]);
#pragma unroll
            for (int j = 0; j < 2; ++j) {
                int row = w * 32 + j * 16 + srow;
                gl2lds16(&Bw[(size_t)(n0 + row) * 512 + (kt + 1) * 32 + sch],
                         &Bs[nxtB + w * 1024 + j * 512]);
            }
        }
        s16x8 af[2], bfr[4];
#pragma unroll
        for (int mt = 0; mt < 2; ++mt)
            af[mt] = *(const s16x8*)&As[curA + (wm * 32 + mt * 16 + l16) * 32 + quad * 8];
#pragma unroll
        for (int nt = 0; nt < 4; ++nt)
            bfr[nt] = *(const s16x8*)&Bs[curB + (wn * 64 + nt * 16 + l16) * 32 + quad * 8];
#pragma unroll
        for (int mt = 0; mt < 2; ++mt)
#pragma unroll
            for (int nt = 0; nt < 4; ++nt)
                acc[mt][nt] = __builtin_amdgcn_mfma_f32_16x16x32_bf16(
                    af[mt], bfr[nt], acc[mt][nt], 0, 0, 0);
    }
}

// ---------------------------------------------------------------------------
// projlg_kernel: blocks 0..767 = QKV projection (job = bx>>8);
// blocks 768..4863 = LGx gate precompute (BW+trans-bound), which has no
// dependency on the projections -> overlaps with the GEMM inside one launch
// instead of serializing as a separate kernel.
// lg: LGx pre-swizzled gate, flat idx ((((b*128+t16)*32+kt)*64)+lane)*16
//     holds log2(sigmoid(gw*SC+gb)+1e-8) for q=t16*16+(lane&15),
//     k=kt*64+kk*16+(lane>>4)*4+reg.
// ---------------------------------------------------------------------------
__global__ __launch_bounds__(256) void projlg_kernel(
    const u16* __restrict__ cQin, const u16* __restrict__ cKV,
    const u16* __restrict__ cW,
    const float* __restrict__ bq, const float* __restrict__ bk,
    const float* __restrict__ bv,
    u16* __restrict__ Qh, u16* __restrict__ Kh, u16* __restrict__ Vt,
    const float* __restrict__ SC, const float* __restrict__ gwp,
    const float* __restrict__ gbp, u16* __restrict__ LGx)
{
    __shared__ __align__(16) u16 As[2 * 4096];
    __shared__ __align__(16) u16 Bs[2 * 4096];
    if (blockIdx.x < 768) {
        const int job = blockIdx.x >> 8;
        const int rem = blockIdx.x & 255;
        const int n0 = (rem & 3) * 128, m0 = (rem >> 2) * 128;
        const u16* A = (job == 0) ? cQin : cKV;
        const u16* W = cW + (size_t)job * 262144;
        const float* bias = (job == 0) ? bq : (job == 1 ? bk : bv);
        f32x4 acc[4][4];
        gemm_core(A, W, m0, n0, As, Bs, acc);

        const int tid = threadIdx.x, lane = tid & 63, w = tid >> 6;
        const int wm = w >> 1, wn = w & 1, l16 = lane & 15, quad = lane >> 4;
#pragma unroll
        for (int nt = 0; nt < 4; ++nt) {
            int j = n0 + wn * 64 + nt * 16 + l16;
            float bj = bias[j];
            int h = j >> 6, d = j & 63;
#pragma unroll
            for (int mt = 0; mt < 4; ++mt) {
                int trow = m0 + wm * 64 + mt * 16 + quad * 4;
                int bb = trow >> 11, nn = trow & 2047;
                int bh = bb * 8 + h;
                if (job == 2) {
                    u16x4 pv;
#pragma unroll
                    for (int reg = 0; reg < 4; ++reg) pv[reg] = f2bf(acc[mt][nt][reg] + bj);
                    *(u16x4*)&Vt[(size_t)(bh * 64 + d) * 2048 + nn] = pv;
                } else if (job == 0) {
#pragma unroll
                    for (int reg = 0; reg < 4; ++reg)
                        Qh[(size_t)(bh * 2048 + nn + reg) * 64 + d] =
                            f2bf((acc[mt][nt][reg] + bj) * QSCALE);
                } else {
#pragma unroll
                    for (int reg = 0; reg < 4; ++reg)
                        Kh[(size_t)(bh * 2048 + nn + reg) * 64 + d] =
                            f2bf(acc[mt][nt][reg] + bj);
                }
            }
        }
    } else {
        const int flat = (blockIdx.x - 768) * 256 + threadIdx.x;
        const int lane = flat & 63;
        const int kt   = (flat >> 6) & 31;
        const int t16  = (flat >> 11) & 127;
        const int b    = flat >> 18;
        const int l16 = lane & 15, quad = lane >> 4;
        const float tA = -gwp[0] * L2E, tB = -gbp[0] * L2E;
        const float* row = SC + ((size_t)b * 2048 + t16 * 16 + l16) * 2048
                              + kt * 64 + quad * 4;
        __align__(16) u16 tmp[16];
#pragma unroll
        for (int kk = 0; kk < 4; ++kk) {
            f32x4 x = *(const f32x4*)(row + kk * 16);
#pragma unroll
            for (int reg = 0; reg < 4; ++reg) {
                float g = __builtin_amdgcn_rcpf(
                    1.0f + __builtin_amdgcn_exp2f(tA * x[reg] + tB)) + 1e-8f;
                tmp[kk * 4 + reg] = f2bf(__builtin_amdgcn_logf(g));  // log2
            }
        }
        u16* d = LGx + (size_t)flat * 16;
        *(uint4*)d       = *(uint4*)tmp;
        *(uint4*)(d + 8) = *(uint4*)(tmp + 8);
    }
}

// ---------------------------------------------------------------------------
// Attention (R5-exact structure, best measured 52.0 us, VGPR 88, no spills).
// Block = 256 thr = 4 fat waves (32 q each, 2 groups); grid (16,8,4) = 2/CU.
// KVBLK=128, 16 tiles, one barrier each. Each K/V fragment read from LDS once
// feeds BOTH q-groups. K tile [128 key][64 d] + V as two [64 d][64 key]
// sub-tiles, 128-B rows, XOR-swizzled (measured conflict-free). LG folded
// into QK^T via MFMA C-init; P redistributed via permlane32+16_swap.
// ---------------------------------------------------------------------------
__global__ __launch_bounds__(256, 2) void attn_kernel(
    const u16* __restrict__ Qh, const u16* __restrict__ Kh,
    const u16* __restrict__ Vt, const u16* __restrict__ LGx,
    u16* __restrict__ Ob)
{
    __shared__ __align__(16) u16 Ks[2][8192];  // [buf][key(128)][d(64)] swz
    __shared__ __align__(16) u16 Vs[2][8192];  // [buf][half(2)][d(64)][key(64)] swz
    const int tid = threadIdx.x;
    const int w = tid >> 6, lane = tid & 63;
    const int l16 = lane & 15, quad = lane >> 4;
    const int b = blockIdx.z, head = blockIdx.y, qg = blockIdx.x;
    const int bh = b * 8 + head;
    const int q0a = qg * 128 + w * 32, q0b = q0a + 16;
    const int t16a = qg * 8 + w * 2;
    const u16* Qp = Qh + (size_t)bh * 131072;
    const u16* Kp = Kh + (size_t)bh * 131072;
    const u16* Vp = Vt + (size_t)bh * 131072;
    const u16* lgPa = LGx + ((size_t)((b * 128 + t16a) * 32) * 64 + lane) * 16;
    const u16* lgPb = LGx + ((size_t)((b * 128 + t16a + 1) * 32) * 64 + lane) * 16;
    const f32x4 vzero = {0.f, 0.f, 0.f, 0.f};
    const s16x8 ones = {0x3F80, 0x3F80, 0x3F80, 0x3F80,
                        0x3F80, 0x3F80, 0x3F80, 0x3F80};  // bf16 1.0 x8

    // precomputed LDS read bases (u16 units); V formulas == K's
    const int s3 = l16 & 7, s2x = s3 & 3, s4x = s3 & 4;
    const int qsw = (quad ^ s2x) * 8;
    const int rb0 = l16 * 64 + qsw + s4x * 8;          // kc even
    const int rb1 = l16 * 64 + qsw + (4 ^ s4x) * 8;    // kc odd
    const u16* KbL = &Ks[0][0];
    const u16* VbL = &Vs[0][0];

    // staging: waves 0-1 K halves, waves 2-3 V halves; 8 slabs each
    const int sr = lane >> 3, c8 = lane & 7;           // 8 rows x 8 chunks
    const bool isK = (w < 2);
    const int hv = w & 1;
    const u16* sgq = isK
        ? (Kp + (size_t)(hv * 64 + sr) * 64 + (c8 ^ sr) * 8)
        : (Vp + (size_t)sr * 2048 + hv * 64 + (c8 ^ sr) * 8);
    const size_t slabAdv = isK ? 512 : 16384;  // +8 rows (u16)
    const size_t tileAdv = isK ? 8192 : 128;   // next 128-key tile (u16)
    u16* sdb = isK ? &Ks[0][hv * 4096] : &Vs[0][hv * 4096];

    s16x8 qfa0 = *(const s16x8*)&Qp[(size_t)(q0a + l16) * 64 + quad * 8];
    s16x8 qfa1 = *(const s16x8*)&Qp[(size_t)(q0a + l16) * 64 + 32 + quad * 8];
    s16x8 qfb0 = *(const s16x8*)&Qp[(size_t)(q0b + l16) * 64 + quad * 8];
    s16x8 qfb1 = *(const s16x8*)&Qp[(size_t)(q0b + l16) * 64 + 32 + quad * 8];
    f32x4 oA[4], oB[4], laccA = vzero, laccB = vzero;
#pragma unroll
    for (int dn = 0; dn < 4; ++dn) { oA[dn] = vzero; oB[dn] = vzero; }

    // prologue: stage tile 0 into buf 0; LG regs for tile 0 (both groups)
#pragma unroll
    for (int j = 0; j < 8; ++j)
        gl2lds16(sgq + (size_t)j * slabAdv, sdb + j * 512);
    sgq += tileAdv;
    uint4 lga0 = *(const uint4*)lgPa;
    uint4 lga1 = *(const uint4*)(lgPa + 8);
    uint4 lga2 = *(const uint4*)(lgPa + 1024);
    uint4 lga3 = *(const uint4*)(lgPa + 1032);
    uint4 lgb0 = *(const uint4*)lgPb;
    uint4 lgb1 = *(const uint4*)(lgPb + 8);
    uint4 lgb2 = *(const uint4*)(lgPb + 1024);
    uint4 lgb3 = *(const uint4*)(lgPb + 1032);
    lgPa += 2048; lgPb += 2048;

// One kk-block (4 key-rows x 2 kc) for BOTH groups; K frags read once.
#define QKQUAD(LA, LB, MA, MB, KOFF)                                           \
    {                                                                          \
        const u32 wda[8] = {LA.x, LA.y, LA.z, LA.w, LB.x, LB.y, LB.z, LB.w};   \
        const u32 wdb[8] = {MA.x, MA.y, MA.z, MA.w, MB.x, MB.y, MB.z, MB.w};   \
        _Pragma("unroll")                                                      \
        for (int kk = 0; kk < 4; ++kk) {                                       \
            s16x8 ka = *(const s16x8*)(KbL + bo + rb0 + kk * 1024);            \
            s16x8 kb = *(const s16x8*)(KbL + bo + rb1 + kk * 1024);            \
            f32x4 ci;                                                          \
            ci[0] = bflo(wda[kk * 2]);     ci[1] = bfhi(wda[kk * 2]);          \
            ci[2] = bflo(wda[kk * 2 + 1]); ci[3] = bfhi(wda[kk * 2 + 1]);      \
            f32x4 s = __builtin_amdgcn_mfma_f32_16x16x32_bf16(ka, qfa0, ci, 0, 0, 0); \
            s = __builtin_amdgcn_mfma_f32_16x16x32_bf16(kb, qfa1, s, 0, 0, 0); \
            f32x4 cj;                                                          \
            cj[0] = bflo(wdb[kk * 2]);     cj[1] = bfhi(wdb[kk * 2]);          \
            cj[2] = bflo(wdb[kk * 2 + 1]); cj[3] = bfhi(wdb[kk * 2 + 1]);      \
            f32x4 t = __builtin_amdgcn_mfma_f32_16x16x32_bf16(ka, qfb0, cj, 0, 0, 0); \
            t = __builtin_amdgcn_mfma_f32_16x16x32_bf16(kb, qfb1, t, 0, 0, 0); \
            PwA[kk][0] = pack_hi(__builtin_amdgcn_exp2f(s[0]),                 \
                                 __builtin_amdgcn_exp2f(s[1]));                \
            PwA[kk][1] = pack_hi(__builtin_amdgcn_exp2f(s[2]),                 \
                                 __builtin_amdgcn_exp2f(s[3]));                \
            PwB[kk][0] = pack_hi(__builtin_amdgcn_exp2f(t[0]),                 \
                                 __builtin_amdgcn_exp2f(t[1]));                \
            PwB[kk][1] = pack_hi(__builtin_amdgcn_exp2f(t[2]),                 \
                                 __builtin_amdgcn_exp2f(t[3]));                \
        }                                                                      \
    }
// note: KOFF handled by caller writing into PwA/PwB at +KOFF via pointer

    for (int kt = 0; kt < 16; ++kt) {
        __syncthreads();  // tile[kt&1] staged, previous reads done
        const int bo = (kt & 1) * 8192;
        if (kt < 15) {    // prefetch tile kt+1 into the other buffer
            u16* dd = sdb + (8192 - bo);
#pragma unroll
            for (int j = 0; j < 8; ++j)
                gl2lds16(sgq + (size_t)j * slabAdv, dd + j * 512);
            sgq += tileAdv;
        }
        __builtin_amdgcn_s_setprio(1);
        // S^T = K.Q^T + LG, P = 2^S^T (bf16-truncated, packed), both groups
        u32 PwA8[8][2], PwB8[8][2];
        {
            u32 (*PwA)[2] = &PwA8[0];
            u32 (*PwB)[2] = &PwB8[0];
            QKQUAD(lga0, lga1, lgb0, lgb1, 0);
        }
        {
            const int bo2 = bo + 4096;  // kk block 4..7 lives 4 rows higher
            u32 (*PwA)[2] = &PwA8[4];
            u32 (*PwB)[2] = &PwB8[4];
            const int bo_save = bo2 - 4096;
            // re-expand with K rows 64..127: base offset += 4*1024
            {
                const u32 wda[8] = {lga2.x, lga2.y, lga2.z, lga2.w,
                                    lga3.x, lga3.y, lga3.z, lga3.w};
                const u32 wdb[8] = {lgb2.x, lgb2.y, lgb2.z, lgb2.w,
                                    lgb3.x, lgb3.y, lgb3.z, lgb3.w};
#pragma unroll
                for (int kk = 0; kk < 4; ++kk) {
                    s16x8 ka = *(const s16x8*)(KbL + bo_save + rb0 + (4 + kk) * 1024);
                    s16x8 kb = *(const s16x8*)(KbL + bo_save + rb1 + (4 + kk) * 1024);
                    f32x4 ci;
                    ci[0] = bflo(wda[kk * 2]);     ci[1] = bfhi(wda[kk * 2]);
                    ci[2] = bflo(wda[kk * 2 + 1]); ci[3] = bfhi(wda[kk * 2 + 1]);
                    f32x4 s = __builtin_amdgcn_mfma_f32_16x16x32_bf16(ka, qfa0, ci, 0, 0, 0);
                    s = __builtin_amdgcn_mfma_f32_16x16x32_bf16(kb, qfa1, s, 0, 0, 0);
                    f32x4 cj;
                    cj[0] = bflo(wdb[kk * 2]);     cj[1] = bfhi(wdb[kk * 2]);
                    cj[2] = bflo(wdb[kk * 2 + 1]); cj[3] = bfhi(wdb[kk * 2 + 1]);
                    f32x4 t = __builtin_amdgcn_mfma_f32_16x16x32_bf16(ka, qfb0, cj, 0, 0, 0);
                    t = __builtin_amdgcn_mfma_f32_16x16x32_bf16(kb, qfb1, t, 0, 0, 0);
                    PwA[kk][0] = pack_hi(__builtin_amdgcn_exp2f(s[0]),
                                         __builtin_amdgcn_exp2f(s[1]));
                    PwA[kk][1] = pack_hi(__builtin_amdgcn_exp2f(s[2]),
                                         __builtin_amdgcn_exp2f(s[3]));
                    PwB[kk][0] = pack_hi(__builtin_amdgcn_exp2f(t[0]),
                                         __builtin_amdgcn_exp2f(t[1]));
                    PwB[kk][1] = pack_hi(__builtin_amdgcn_exp2f(t[2]),
                                         __builtin_amdgcn_exp2f(t[3]));
                }
            }
        }
        if (kt < 15) {    // register-prefetch LG for tile kt+1
            lga0 = *(const uint4*)lgPa;
            lga1 = *(const uint4*)(lgPa + 8);
            lga2 = *(const uint4*)(lgPa + 1024);
            lga3 = *(const uint4*)(lgPa + 1032);
            lgb0 = *(const uint4*)lgPb;
            lgb1 = *(const uint4*)(lgPb + 8);
            lgb2 = *(const uint4*)(lgPb + 1024);
            lgb3 = *(const uint4*)(lgPb + 1032);
            lgPa += 2048; lgPb += 2048;
        }
        // PV + row-sum over 4 key-chunks of 32; V frags read once per chunk
#pragma unroll
        for (int kc = 0; kc < 4; ++kc) {
            union { u32 wrd[4]; s16x8 v; } pa, pb;
#pragma unroll
            for (int i = 0; i < 2; ++i) {
                u32x2 r1 = __builtin_amdgcn_permlane32_swap(
                    PwA8[2 * kc][i], PwA8[2 * kc + 1][i], false, false);
                u32x2 r2 = __builtin_amdgcn_permlane16_swap(
                    r1[0], r1[1], false, false);
                pa.wrd[i]     = r2[0];
                pa.wrd[2 + i] = r2[1];
                u32x2 r3 = __builtin_amdgcn_permlane32_swap(
                    PwB8[2 * kc][i], PwB8[2 * kc + 1][i], false, false);
                u32x2 r4 = __builtin_amdgcn_permlane16_swap(
                    r3[0], r3[1], false, false);
                pb.wrd[i]     = r4[0];
                pb.wrd[2 + i] = r4[1];
            }
            s16x8 pfa = pa.v, pfb = pb.v;
            laccA = __builtin_amdgcn_mfma_f32_16x16x32_bf16(pfa, ones, laccA, 0, 0, 0);
            laccB = __builtin_amdgcn_mfma_f32_16x16x32_bf16(pfb, ones, laccB, 0, 0, 0);
            const int vbb = ((kc & 1) ? rb1 : rb0) + (kc >> 1) * 4096 + bo;
#pragma unroll
            for (int dn = 0; dn < 4; ++dn) {
                s16x8 vf = *(const s16x8*)(VbL + vbb + dn * 1024);
                oA[dn] = __builtin_amdgcn_mfma_f32_16x16x32_bf16(
                    pfa, vf, oA[dn], 0, 0, 0);
                oB[dn] = __builtin_amdgcn_mfma_f32_16x16x32_bf16(
                    pfb, vf, oB[dn], 0, 0, 0);
            }
        }
        __builtin_amdgcn_s_setprio(0);
    }
#undef QKQUAD
    // lacc[reg] = sum_k P[q=quad*4+reg][k] — exactly the row this lane stores
#pragma unroll
    for (int reg = 0; reg < 4; ++reg) {
        float invA = __builtin_amdgcn_rcpf(laccA[reg]);
        float invB = __builtin_amdgcn_rcpf(laccB[reg]);
        int trowA = b * 2048 + q0a + quad * 4 + reg;
        int trowB = b * 2048 + q0b + quad * 4 + reg;
#pragma unroll
        for (int dn = 0; dn < 4; ++dn) {
            Ob[(size_t)trowA * 512 + head * 64 + dn * 16 + l16] =
                f2bf(oA[dn][reg] * invA);
            Ob[(size_t)trowB * 512 + head * 64 + dn * 16 + l16] =
                f2bf(oB[dn][reg] * invB);
        }
    }
}

// ---------------------------------------------------------------------------
// Output projection: out = Ob @ Wo^T + bo, fp32 out. 64x128 tiles, 2 blocks/CU.
// ---------------------------------------------------------------------------
__global__ __launch_bounds__(256) void out_kernel(
    const u16* __restrict__ Ob, const u16* __restrict__ cWo,
    const float* __restrict__ bo, float* __restrict__ out)
{
    __shared__ __align__(16) u16 As[2 * 2048];
    __shared__ __align__(16) u16 Bs[2 * 4096];
    const int m0 = blockIdx.y * 64, n0 = blockIdx.x * 128;
    f32x4 acc[2][4];
    gemm_core_m64(Ob, cWo, m0, n0, As, Bs, acc);
    const int tid = threadIdx.x, lane = tid & 63, w = tid >> 6;
    const int wm = w & 1, wn = w >> 1, l16 = lane & 15, quad = lane >> 4;
#pragma unroll
    for (int nt = 0; nt < 4; ++nt) {
        int j = n0 + wn * 64 + nt * 16 + l16;
        float bj = bo[j];
#pragma unroll
        for (int mt = 0; mt < 2; ++mt) {
            int t = m0 + wm * 32 + mt * 16 + quad * 4;
#pragma unroll
            for (int reg = 0; reg < 4; ++reg)
                out[(size_t)(t + reg) * 512 + j] = acc[mt][nt][reg] + bj;
        }
    }
}

extern "C" void kernel_launch(void* const* d_in, const int* in_sizes, int n_in,
                              void* d_out, int out_size, void* d_ws, size_t ws_size,
                              hipStream_t stream)
{
    const float* Qin  = (const float*)d_in[0];
    const float* KVin = (const float*)d_in[1];
    const float* SC   = (const float*)d_in[2];
    const float* Wq   = (const float*)d_in[3];
    const float* bq   = (const float*)d_in[4];
    const float* Wk   = (const float*)d_in[5];
    const float* bk   = (const float*)d_in[6];
    const float* Wv   = (const float*)d_in[7];
    const float* bv   = (const float*)d_in[8];
    const float* gw   = (const float*)d_in[9];
    const float* gb   = (const float*)d_in[10];
    const float* Wo   = (const float*)d_in[11];
    const float* bo   = (const float*)d_in[12];
    float* out = (float*)d_out;

    // ws layout (u16 units): conv 9.4M | Qh/Kh/Vt/Ob 4.2M each | LGx 16.8M
    u16* conv = (u16*)d_ws;
    u16* cQin = conv;
    u16* cKV  = conv + 4194304;
    u16* cW   = conv + 8388608;        // Wq,Wk,Wv,Wo each 262,144
    u16* Qh   = conv + 9437184;
    u16* Kh   = Qh + 4194304;
    u16* Vt   = Kh + 4194304;
    u16* Ob   = Vt + 4194304;
    u16* LGx  = Ob + 4194304;          // 16,777,216 u16 = 32 MiB

    hipLaunchKernelGGL(conv_kernel, dim3(9216), dim3(256), 0, stream,
                       Qin, KVin, Wq, Wk, Wv, Wo, conv);
    hipLaunchKernelGGL(projlg_kernel, dim3(4864), dim3(256), 0, stream,
                       cQin, cKV, cW, bq, bk, bv, Qh, Kh, Vt,
                       SC, gw, gb, LGx);
    hipLaunchKernelGGL(attn_kernel, dim3(16, 8, 4), dim3(256), 0, stream,
                       Qh, Kh, Vt, LGx, Ob);
    hipLaunchKernelGGL(out_kernel, dim3(4, 128), dim3(256), 0, stream,
                       Ob, cW + 786432, bo, out);
}